// Round 5
// baseline (135.022 us; speedup 1.0000x reference)
//
#include <hip/hip_runtime.h>
#include <hip/hip_bf16.h>

// MoEStage: B=32 T=2048 DM=128 DFE=64 DH=64 DRH=64 E=8 NF=16 NSF=64 TOPK=2
// K0a: LDS-tiled weight folds + transposes + identity flags (25 role blocks)
// K1 : LN (2 lanes/token) + tiled f32 router GEMM acc[8][4] + top2 + lists
// K2 : per-expert gathered MFMA dual-GEMM, weights direct-from-L2 -> eoTok
// K3 : out = hidden + alpha*(g1*eo1 + g2*eo2)

typedef unsigned short u16;
typedef __attribute__((ext_vector_type(8))) short bfrag;
typedef __attribute__((ext_vector_type(8))) u16 u16x8;
typedef __attribute__((ext_vector_type(4))) float facc;
typedef __attribute__((ext_vector_type(4))) float f32x4;

#define NTOK 65536
#define CAP 65536

// ws layout (bytes). [0,32): cnt. [64,128): flags (flags[0]=sidOK, flags[1+e]=eidx base or -1)
#define OFF_CNT   ((size_t)0)
#define OFF_FLG   ((size_t)64)
#define OFF_LTOK  ((size_t)512)
#define OFF_SMAPG (OFF_LTOK + (size_t)8*CAP*4)
#define OFF_HWS   (OFF_SMAPG + (size_t)NTOK*8)
#define OFF_EOTOK (OFF_HWS + (size_t)NTOK*128*2)
#define OFF_W1T   (OFF_EOTOK + (size_t)NTOK*2*128*2)   // 8*64*160*2
#define OFF_W2T   (OFF_W1T + 163840)                   // 8*128*64*2
#define OFF_B1P   (OFF_W2T + 131072)                   // 8*64*4
#define OFF_WPR   (OFF_B1P + 2048)                     // 64*64*4
#define OFF_BR1P  (OFF_WPR + 16384)                    // 64*4

__device__ __forceinline__ u16 f2bf(float f) {
  union { __hip_bfloat16 h; u16 u; } cv;
  cv.h = __float2bfloat16(f);
  return cv.u;
}
__device__ __forceinline__ float bf2f(u16 u) {
  return __uint_as_float(((unsigned)u) << 16);
}

// ---------------- K0a: folds + transposes + flags (role blocks) ----------------
__global__ __launch_bounds__(256)
void k0a_pre(const float* __restrict__ Wp, const float* __restrict__ bp,
             const float* __restrict__ Wr1, const float* __restrict__ br1,
             const float* __restrict__ Wf, const float* __restrict__ bfv,
             const float* __restrict__ We1h, const float* __restrict__ We1f,
             const float* __restrict__ be1, const float* __restrict__ We2,
             const int* __restrict__ eidx_g, const int* __restrict__ sidx_g,
             float* __restrict__ Wpr, float* __restrict__ br1p,
             u16* __restrict__ w1t, u16* __restrict__ w2t, float* __restrict__ b1p,
             int* __restrict__ flags)
{
  __shared__ float smA[64*68];      // 17.4KB
  __shared__ float smB[128*68];     // 34.8KB (role 9..16 uses 128 rows)
  int b = blockIdx.x, tid = threadIdx.x;

  if (b == 0) {
    // Wpr[i][o] = sum_k Wp[i][k]*Wr1[128+k][o]; br1p; sid flag
    for (int idx = tid; idx < 4096; idx += 256) {
      int r = idx >> 6, c = idx & 63;
      smA[r*68 + c] = Wp[idx];                 // Wp[i][k] at smA[i*68+k]
      smB[r*68 + c] = Wr1[128*64 + idx];       // Wt[k][o] at smB[k*68+o]
    }
    if (tid == 0) { int ok = 1; for (int i = 0; i < 64; ++i) ok &= (sidx_g[i] == i); flags[0] = ok; }
    __syncthreads();
    int i = tid >> 2, oq = (tid & 3) * 16;
    f32x4 acc[4];
    #pragma unroll
    for (int m = 0; m < 4; ++m) { f32x4 z = {0,0,0,0}; acc[m] = z; }
    for (int k = 0; k < 64; ++k) {
      float a = smA[i*68 + k];
      #pragma unroll
      for (int m = 0; m < 4; ++m) {
        f32x4 b4 = *(const f32x4*)(smB + k*68 + oq + m*4);
        #pragma unroll
        for (int j = 0; j < 4; ++j) acc[m][j] = fmaf(a, b4[j], acc[m][j]);
      }
    }
    #pragma unroll
    for (int m = 0; m < 4; ++m) *(f32x4*)(Wpr + i*64 + oq + m*4) = acc[m];
    if (tid < 64) {
      float s = br1[tid];
      for (int k = 0; k < 64; ++k) s = fmaf(bp[k], smB[k*68 + tid], s);
      br1p[tid] = s;
    }
  } else if (b <= 8) {
    // F[e] = Wf[e]@We1f[e] -> w1t[..][128+i]; b1p; zero pad; eidx flag
    int e = b - 1;
    for (int idx = tid; idx < 4096; idx += 256) {
      int r = idx >> 6, c = idx & 63;
      smB[r*68 + c] = We1f[e*4096 + idx];      // [d][jj]
    }
    for (int idx = tid; idx < 1024; idx += 256) {
      int r = idx >> 6, c = idx & 63;
      smA[r*68 + c] = Wf[e*1024 + idx];        // [i][d]
    }
    if (tid == 0) {
      int s0 = eidx_g[e*16]; int ok = 1;
      for (int i = 0; i < 16; ++i) ok &= (eidx_g[e*16 + i] == s0 + i);
      flags[1 + e] = ok ? s0 : -1;
    }
    __syncthreads();
    int i = tid >> 4, jq = (tid & 15) * 4;
    f32x4 acc = {0,0,0,0};
    for (int d = 0; d < 64; ++d) {
      float a = smA[i*68 + d];
      f32x4 b4 = *(const f32x4*)(smB + d*68 + jq);
      #pragma unroll
      for (int j = 0; j < 4; ++j) acc[j] = fmaf(a, b4[j], acc[j]);
    }
    #pragma unroll
    for (int j = 0; j < 4; ++j) w1t[(size_t)(e*64 + jq + j)*160 + 128 + i] = f2bf(acc[j]);
    if (tid < 64) {
      float s = be1[e*64 + tid];
      for (int d = 0; d < 64; ++d) s = fmaf(bfv[e*64 + d], smB[d*68 + tid], s);
      b1p[e*64 + tid] = s;
    }
    // zero pad k in [144,160)
    for (int idx = tid; idx < 1024; idx += 256) {
      int jj = idx >> 4, kk = idx & 15;
      w1t[(size_t)(e*64 + jj)*160 + 144 + kk] = 0;
    }
  } else if (b <= 16) {
    // transpose We1h[e] (128x64) -> w1t[e][jj][k], k<128
    int e = b - 9;
    for (int idx = tid; idx < 8192; idx += 256) {
      int r = idx >> 6, c = idx & 63;
      smB[r*68 + c] = We1h[(size_t)e*8192 + idx];   // [k][jj]
    }
    __syncthreads();
    int jj = tid & 63, kb = (tid >> 6) * 32;
    #pragma unroll
    for (int m = 0; m < 4; ++m) {
      u16x8 o;
      #pragma unroll
      for (int q = 0; q < 8; ++q) o[q] = f2bf(smB[(kb + m*8 + q)*68 + jj]);
      *(u16x8*)(w1t + (size_t)(e*64 + jj)*160 + kb + m*8) = o;
    }
  } else if (b <= 24) {
    // transpose We2[e] (64x128) -> w2t[e][d][k]
    int e = b - 17;
    for (int idx = tid; idx < 8192; idx += 256) {
      int r = idx >> 7, c = idx & 127;
      smB[r*132 + c] = We2[(size_t)e*8192 + idx];   // [k][d], pad 132
    }
    __syncthreads();
    int d = tid & 127, kb = (tid >> 7) * 32;
    #pragma unroll
    for (int m = 0; m < 4; ++m) {
      u16x8 o;
      #pragma unroll
      for (int q = 0; q < 8; ++q) o[q] = f2bf(smB[(kb + m*8 + q)*132 + d]);
      *(u16x8*)(w2t + (size_t)(e*128 + d)*64 + kb + m*8) = o;
    }
  }
}

// ---------------- K1: LN + f32 router GEMM acc[8][4] + top2 + lists ----------------
// 256 thr = 4 waves, 128 tokens/block, grid 512. LN: 2 lanes/token (64 cols each).
// At: [64 rows][128 tok] f32, row=512B, 16 slots of 32B, slot = (tok>>3)^(kr&15).
// Chunk order {2(feat/Wpr), 0, 1}. Phase C unions ltok/tg into At.
__global__ __launch_bounds__(256, 3)
void k1_router(const float* __restrict__ hidden, const float* __restrict__ feat,
               const float* __restrict__ ln_g, const float* __restrict__ ln_b,
               const float* __restrict__ Wr1, const float* __restrict__ Wr2,
               const float* __restrict__ br2, const int* __restrict__ seqlen,
               const int* __restrict__ sidx_g,
               const float* __restrict__ Wpr, const float* __restrict__ br1p,
               const int* __restrict__ flags,
               float* __restrict__ outG, float* __restrict__ outP,
               u16* __restrict__ hws, int* __restrict__ cnt,
               int* __restrict__ listTok, float* __restrict__ smapG)
{
  __shared__ __align__(16) char smemAt[64*128*4];   // 32KB: At, then ltok/tg in phase C
  __shared__ float Wc[64*64];                        // 16KB
  __shared__ float sg[128], sb[128], sb1[64], sbr2[8];
  __shared__ int ssidx[64];
  __shared__ int lcnt[8], lbase[8];
  float* At = (float*)smemAt;
  int* ltok = (int*)smemAt;                 // [8][128] = 4KB
  float* tgp = (float*)(smemAt + 4096);     // [128][2] = 1KB

  int tid = threadIdx.x;

  // prefetch Wpr chunk (chunk order 2 first)
  f32x4 wpf[4];
  #pragma unroll
  for (int u = 0; u < 4; ++u) wpf[u] = ((const f32x4*)Wpr)[u*256 + tid];

  if (tid < 128) sg[tid] = ln_g[tid]; else sb[tid-128] = ln_b[tid-128];
  if (tid < 64) { sb1[tid] = br1p[tid]; ssidx[tid] = sidx_g[tid]; }
  if (tid >= 64 && tid < 72) sbr2[tid-64] = br2[tid-64];
  if (tid >= 72 && tid < 80) lcnt[tid-72] = 0;
  int sidok = flags[0];

  int tl = tid >> 1, hq = tid & 1;          // token-local, col half
  int t = blockIdx.x * 128 + tl;

  // ---- Phase A: LN ----
  f32x4 x[16];
  #pragma unroll
  for (int i = 0; i < 16; ++i) x[i] = *(const f32x4*)(hidden + (size_t)t*128 + hq*64 + i*4);
  float s = 0.f;
  #pragma unroll
  for (int i = 0; i < 16; ++i) { s += x[i][0] + x[i][1]; s += x[i][2] + x[i][3]; }
  s += __shfl_xor(s, 1, 64);
  float mu = s * (1.f/128.f);
  float v = 0.f;
  #pragma unroll
  for (int i = 0; i < 16; ++i) {
    #pragma unroll
    for (int j = 0; j < 4; ++j) { float d = x[i][j] - mu; v = fmaf(d, d, v); }
  }
  v += __shfl_xor(v, 1, 64);
  float rs = rsqrtf(v * (1.f/128.f) + 1e-5f);
  #pragma unroll
  for (int i = 0; i < 16; ++i) {
    #pragma unroll
    for (int j = 0; j < 4; ++j) {
      int c = hq*64 + i*4 + j;
      x[i][j] = (x[i][j] - mu) * rs * sg[c] + sb[c];
    }
  }
  #pragma unroll
  for (int m = 0; m < 8; ++m) {
    u16x8 o;
    #pragma unroll
    for (int j = 0; j < 4; ++j) { o[j] = f2bf(x[2*m][j]); o[4+j] = f2bf(x[2*m+1][j]); }
    *(u16x8*)(hws + (size_t)t*128 + hq*64 + m*8) = o;
  }
  // feat -> At (chunk 2 content), rows kr = hq*32 + i
  int tb8 = tl >> 3, t7 = (tl & 7) << 2;
  if (sidok) {
    #pragma unroll
    for (int m = 0; m < 8; ++m) {
      f32x4 fv = *(const f32x4*)(feat + (size_t)t*64 + hq*32 + m*4);
      #pragma unroll
      for (int j = 0; j < 4; ++j) {
        int kr = hq*32 + m*4 + j;
        *(float*)((char*)At + (kr << 9) + (((tb8 ^ (kr & 15)) & 15) << 5) + t7) = fv[j];
      }
    }
  } else {
    #pragma unroll
    for (int i = 0; i < 32; ++i) {
      int kr = hq*32 + i;
      float fv = feat[(size_t)t*64 + ssidx[kr]];
      *(float*)((char*)At + (kr << 9) + (((tb8 ^ (kr & 15)) & 15) << 5) + t7) = fv;
    }
  }

  // ---- Phase B: chunks {2,0,1} ----
  float acc[8][4];
  #pragma unroll
  for (int i = 0; i < 8; ++i)
    #pragma unroll
    for (int p = 0; p < 4; ++p) acc[i][p] = 0.f;

  int g8 = tid >> 4;                   // 8-token group this lane computes
  int ob = (tid & 15) * 4;

  #pragma unroll 1
  for (int ci = 0; ci < 3; ++ci) {
    // stage At for h chunks (lanes owning those cols)
    if (ci == 1 && hq == 0) {
      #pragma unroll
      for (int i = 0; i < 16; ++i)
        #pragma unroll
        for (int j = 0; j < 4; ++j) {
          int kr = i*4 + j;
          *(float*)((char*)At + (kr << 9) + (((tb8 ^ (kr & 15)) & 15) << 5) + t7) = x[i][j];
        }
    }
    if (ci == 2 && hq == 1) {
      #pragma unroll
      for (int i = 0; i < 16; ++i)
        #pragma unroll
        for (int j = 0; j < 4; ++j) {
          int kr = i*4 + j;
          *(float*)((char*)At + (kr << 9) + (((tb8 ^ (kr & 15)) & 15) << 5) + t7) = x[i][j];
        }
    }
    // stage Wc from prefetch regs
    #pragma unroll
    for (int u = 0; u < 4; ++u) ((f32x4*)Wc)[u*256 + tid] = wpf[u];
    __syncthreads();
    // prefetch next W chunk
    if (ci < 2) {
      const f32x4* nsrc = (ci == 0) ? (const f32x4*)Wr1 : (const f32x4*)(Wr1 + 4096);
      #pragma unroll
      for (int u = 0; u < 4; ++u) wpf[u] = nsrc[u*256 + tid];
    }
    #pragma unroll 4
    for (int k = 0; k < 64; ++k) {
      int base = (k << 7) + (((g8 ^ (k & 15)) & 15) << 3);
      f32x4 a0 = *(const f32x4*)(At + base);
      f32x4 a1 = *(const f32x4*)(At + base + 4);
      f32x4 b4 = *(const f32x4*)(Wc + k*64 + ob);
      #pragma unroll
      for (int i = 0; i < 4; ++i)
        #pragma unroll
        for (int p = 0; p < 4; ++p) {
          acc[i][p]   = fmaf(a0[i], b4[p], acc[i][p]);
          acc[4+i][p] = fmaf(a1[i], b4[p], acc[4+i][p]);
        }
    }
    __syncthreads();
  }

  // ---- Phase C: logits, softmax, top2 (At now unioned as ltok/tg) ----
  float w2r[4][8];
  #pragma unroll
  for (int p = 0; p < 4; ++p) {
    f32x4 wlo = *(const f32x4*)(Wr2 + (ob + p)*8);
    f32x4 whi = *(const f32x4*)(Wr2 + (ob + p)*8 + 4);
    #pragma unroll
    for (int e = 0; e < 4; ++e) { w2r[p][e] = wlo[e]; w2r[p][4+e] = whi[e]; }
  }
  float b1r[4];
  #pragma unroll
  for (int p = 0; p < 4; ++p) b1r[p] = sb1[ob + p];

  int j16 = tid & 15;
  #pragma unroll 1
  for (int ti = 0; ti < 8; ++ti) {
    float lo[8];
    #pragma unroll
    for (int e = 0; e < 8; ++e) lo[e] = 0.f;
    #pragma unroll
    for (int p = 0; p < 4; ++p) {
      float z = fmaxf(acc[ti][p] + b1r[p], 0.f);
      #pragma unroll
      for (int e = 0; e < 8; ++e) lo[e] = fmaf(z, w2r[p][e], lo[e]);
    }
    #pragma unroll
    for (int m = 1; m < 16; m <<= 1) {
      #pragma unroll
      for (int e = 0; e < 8; ++e) lo[e] += __shfl_xor(lo[e], m, 64);
    }
    #pragma unroll
    for (int e = 0; e < 8; ++e) lo[e] += sbr2[e];

    int tloc = g8*8 + ti;
    int tt = blockIdx.x*128 + tloc;
    float mx = lo[0];
    #pragma unroll
    for (int e = 1; e < 8; ++e) mx = fmaxf(mx, lo[e]);
    float ex[8]; float ss = 0.f;
    #pragma unroll
    for (int e = 0; e < 8; ++e) { ex[e] = __expf(lo[e] - mx); ss += ex[e]; }
    float inv = 1.f / ss;
    float p[8];
    #pragma unroll
    for (int e = 0; e < 8; ++e) p[e] = ex[e] * inv;
    float p1 = p[0]; int i1 = 0;
    #pragma unroll
    for (int e = 1; e < 8; ++e) { bool tk2 = p[e] > p1; p1 = tk2 ? p[e] : p1; i1 = tk2 ? e : i1; }
    float p2 = -1.f; int i2 = 0;
    #pragma unroll
    for (int e = 0; e < 8; ++e) { bool tk2 = (e != i1) && (p[e] > p2); p2 = tk2 ? p[e] : p2; i2 = tk2 ? e : i2; }
    bool valid = (tt & 2047) < seqlen[tt >> 11];
    float gden = 1.f / (p1 + p2);
    float g1 = p1 * gden, g2 = p2 * gden;
    float pv = p[0];
    #pragma unroll
    for (int e = 1; e < 8; ++e) pv = (j16 == e) ? p[e] : pv;
    if (j16 < 8) outP[(size_t)tt*8 + j16] = pv;
    float gv = (j16 == i1) ? g1 : ((j16 == i2) ? g2 : 0.f);
    if (!valid) gv = 0.f;
    if (j16 < 8) outG[(size_t)tt*8 + j16] = gv;
    if (j16 == 0) {
      if (valid) {
        int lp = atomicAdd(&lcnt[i1], 1); if (lp < 128) ltok[i1*128 + lp] = (tt << 1);
        lp = atomicAdd(&lcnt[i2], 1);     if (lp < 128) ltok[i2*128 + lp] = (tt << 1) | 1;
        tgp[tloc*2] = g1; tgp[tloc*2+1] = g2;
      } else {
        tgp[tloc*2] = 0.f; tgp[tloc*2+1] = 0.f;
      }
    }
  }

  __syncthreads();
  if (tid < 8) { int n8 = min(lcnt[tid], 128); lbase[tid] = atomicAdd(&cnt[tid], n8); }
  __syncthreads();
  #pragma unroll 1
  for (int e = 0; e < 8; ++e) {
    int ncnt = min(lcnt[e], 128);
    if (tid < ncnt) listTok[(size_t)e*CAP + lbase[e] + tid] = ltok[e*128 + tid];
  }
  if (tid < 128) {
    float2 g; g.x = tgp[tid*2]; g.y = tgp[tid*2+1];
    ((float2*)smapG)[blockIdx.x*128 + tid] = g;
  }
}

// ---------------- K2: gathered expert MFMA dual-GEMM -> eoTok ----------------
__global__ __launch_bounds__(256)
void k2_experts(const float* __restrict__ feat, const u16* __restrict__ hws,
                const u16* __restrict__ w1t, const u16* __restrict__ w2t,
                const float* __restrict__ b1p, const float* __restrict__ be2,
                const int* __restrict__ eidx_g, const int* __restrict__ cnt,
                const int* __restrict__ listTok, const int* __restrict__ flags,
                u16* __restrict__ eoTok)
{
  __shared__ u16 Xs[64*168];    // 336B rows: h(256) feat(32) zero(32) pad(16)
  __shared__ u16 H1s[64*88];    // 176B rows
  __shared__ float b1s[64], be2s[128];
  __shared__ int sent[64];
  __shared__ int seidx[16];
  __shared__ int snr;

  int b = blockIdx.x, tid = threadIdx.x;
  int e = -1, row0 = 0, n = 0, accb = 0;
  #pragma unroll
  for (int i = 0; i < 8; ++i) {
    int ci = cnt[i]; int ns = (ci + 63) >> 6;
    if (e < 0 && b < accb + ns) { e = i; row0 = (b - accb) << 6; n = ci; }
    accb += ns;
  }
  if (e < 0) return;
  int nr = n - row0; if (nr > 64) nr = 64;
  if (tid == 0) snr = nr;
  int fb = flags[1 + e];

  if (tid < 64) {
    int ent = (tid < nr) ? listTok[(size_t)e*CAP + row0 + tid] : 0;
    sent[tid] = ent;
    b1s[tid] = b1p[e*64 + tid];
  } else if (tid < 192) {
    be2s[tid - 64] = be2[e*128 + tid - 64];
  } else if (tid < 208) {
    seidx[tid-192] = eidx_g[e*16 + tid - 192];
  }
  __syncthreads();

  for (int c2 = tid; c2 < 1024; c2 += 256) {
    int r = c2 >> 4, p = c2 & 15;
    u16x8 vv = *(const u16x8*)(hws + (size_t)(sent[r] >> 1)*128 + p*8);
    *(u16x8*)((char*)Xs + r*336 + p*16) = vv;
  }
  if (tid < 128) {
    int r = tid >> 1, hf = tid & 1;
    int tk = sent[r] >> 1;
    u16x8 ov;
    if (fb >= 0) {
      f32x4 v0 = *(const f32x4*)(feat + (size_t)tk*64 + fb + hf*8);
      f32x4 v1 = *(const f32x4*)(feat + (size_t)tk*64 + fb + hf*8 + 4);
      #pragma unroll
      for (int q = 0; q < 4; ++q) { ov[q] = f2bf(v0[q]); ov[4+q] = f2bf(v1[q]); }
    } else {
      #pragma unroll
      for (int q = 0; q < 8; ++q) ov[q] = f2bf(feat[(size_t)tk*64 + seidx[hf*8 + q]]);
    }
    *(u16x8*)((char*)Xs + r*336 + 256 + hf*16) = ov;
    u16x8 zv = {0,0,0,0,0,0,0,0};
    *(u16x8*)((char*)Xs + r*336 + 288 + hf*16) = zv;
  }
  __syncthreads();

  int w = tid >> 6, lane = tid & 63;
  int la = lane & 15, lg = lane >> 4;
  const u16* w1e = w1t + (size_t)e*64*160;
  const u16* w2e = w2t + (size_t)e*128*64;

  facc acc[4];
  #pragma unroll
  for (int ni = 0; ni < 4; ++ni) { facc z = {0.f,0.f,0.f,0.f}; acc[ni] = z; }
  #pragma unroll
  for (int kc = 0; kc < 5; ++kc) {
    int r = w*16 + la;
    bfrag af = *(const bfrag*)((const char*)Xs + r*336 + kc*64 + lg*16);
    #pragma unroll
    for (int ni = 0; ni < 4; ++ni) {
      bfrag bf2 = *(const bfrag*)(w1e + (size_t)(ni*16 + la)*160 + kc*32 + lg*8);
      acc[ni] = __builtin_amdgcn_mfma_f32_16x16x32_bf16(af, bf2, acc[ni], 0, 0, 0);
    }
  }
  #pragma unroll
  for (int ni = 0; ni < 4; ++ni)
    #pragma unroll
    for (int rg = 0; rg < 4; ++rg) {
      int r = w*16 + lg*4 + rg;
      int c = ni*16 + la;
      float z = acc[ni][rg] + b1s[c];
      float gl = 0.5f * z * (1.f + erff(z * 0.70710678118f));
      *(u16*)((char*)H1s + r*176 + c*2) = f2bf(gl);
    }
  __syncthreads();

  facc acc2[8];
  #pragma unroll
  for (int ni = 0; ni < 8; ++ni) { facc z = {0.f,0.f,0.f,0.f}; acc2[ni] = z; }
  #pragma unroll
  for (int kc = 0; kc < 2; ++kc) {
    int r = w*16 + la;
    bfrag af = *(const bfrag*)((const char*)H1s + r*176 + kc*64 + lg*16);
    #pragma unroll
    for (int ni = 0; ni < 8; ++ni) {
      bfrag bf2 = *(const bfrag*)(w2e + (size_t)(ni*16 + la)*64 + kc*32 + lg*8);
      acc2[ni] = __builtin_amdgcn_mfma_f32_16x16x32_bf16(af, bf2, acc2[ni], 0, 0, 0);
    }
  }
  #pragma unroll
  for (int ni = 0; ni < 8; ++ni)
    #pragma unroll
    for (int rg = 0; rg < 4; ++rg) {
      int r = w*16 + lg*4 + rg;
      int c = ni*16 + la;
      if (r < snr) {
        float vv = acc2[ni][rg] + be2s[c];
        eoTok[(size_t)sent[r]*128 + c] = f2bf(vv);
      }
    }
}

// ---------------- K3: combine ----------------
__global__ __launch_bounds__(256)
void k3_combine(const float* __restrict__ hidden, const float* __restrict__ smapG,
                const u16* __restrict__ eoTok, const float* __restrict__ alphap,
                float* __restrict__ outN)
{
  int tid = threadIdx.x;
  int tok = tid >> 2, q = tid & 3;
  int t = blockIdx.x*64 + tok;
  float2 g = ((const float2*)smapG)[t];
  float a = alphap[0];
  float ag0 = a * g.x, ag1 = a * g.y;
  const f32x4* hp = (const f32x4*)(hidden + (size_t)t*128 + q*32);
  f32x4* op = (f32x4*)(outN + (size_t)t*128 + q*32);
  const u16x8* e0 = (const u16x8*)(eoTok + ((size_t)t*2)*128 + q*32);
  const u16x8* e1 = (const u16x8*)(eoTok + ((size_t)t*2 + 1)*128 + q*32);
  #pragma unroll
  for (int i = 0; i < 4; ++i) {
    f32x4 r0 = hp[2*i], r1 = hp[2*i+1];
    if (g.x != 0.f) {
      u16x8 x0 = e0[i];
      #pragma unroll
      for (int j = 0; j < 4; ++j) { r0[j] = fmaf(ag0, bf2f(x0[j]), r0[j]); r1[j] = fmaf(ag0, bf2f(x0[4+j]), r1[j]); }
    }
    if (g.y != 0.f) {
      u16x8 x1 = e1[i];
      #pragma unroll
      for (int j = 0; j < 4; ++j) { r0[j] = fmaf(ag1, bf2f(x1[j]), r0[j]); r1[j] = fmaf(ag1, bf2f(x1[4+j]), r1[j]); }
    }
    op[2*i] = r0; op[2*i+1] = r1;
  }
}

// ---------------- launch ----------------
extern "C" void kernel_launch(void* const* d_in, const int* in_sizes, int n_in,
                              void* d_out, int out_size, void* d_ws, size_t ws_size,
                              hipStream_t stream) {
  const float* hidden = (const float*)d_in[0];
  const float* feat   = (const float*)d_in[1];
  const float* ln_g   = (const float*)d_in[2];
  const float* ln_b   = (const float*)d_in[3];
  const float* Wp     = (const float*)d_in[4];
  const float* bp     = (const float*)d_in[5];
  const float* Wr1    = (const float*)d_in[6];
  const float* br1    = (const float*)d_in[7];
  const float* Wr2    = (const float*)d_in[8];
  const float* br2    = (const float*)d_in[9];
  const float* Wf     = (const float*)d_in[10];
  const float* bfv    = (const float*)d_in[11];
  const float* We1h   = (const float*)d_in[12];
  const float* We1f   = (const float*)d_in[13];
  const float* be1    = (const float*)d_in[14];
  const float* We2    = (const float*)d_in[15];
  const float* be2    = (const float*)d_in[16];
  const float* alpha  = (const float*)d_in[17];
  const int* seqlen   = (const int*)d_in[18];
  const int* eidx     = (const int*)d_in[19];
  const int* sidx     = (const int*)d_in[20];

  char* ws = (char*)d_ws;
  int*   cnt      = (int*)(ws + OFF_CNT);
  int*   flags    = (int*)(ws + OFF_FLG);
  int*   listTok  = (int*)(ws + OFF_LTOK);
  float* smapG    = (float*)(ws + OFF_SMAPG);
  u16*   hws      = (u16*)(ws + OFF_HWS);
  u16*   eoTok    = (u16*)(ws + OFF_EOTOK);
  u16*   w1t      = (u16*)(ws + OFF_W1T);
  u16*   w2t      = (u16*)(ws + OFF_W2T);
  float* b1p      = (float*)(ws + OFF_B1P);
  float* Wpr      = (float*)(ws + OFF_WPR);
  float* br1p     = (float*)(ws + OFF_BR1P);

  float* outN = (float*)d_out;
  float* outG = outN + (size_t)NTOK * 128;
  float* outP = outG + (size_t)NTOK * 8;

  hipMemsetAsync(ws + OFF_CNT, 0, 256, stream);
  k0a_pre<<<25, 256, 0, stream>>>(Wp, bp, Wr1, br1, Wf, bfv, We1h, We1f, be1, We2,
                                  eidx, sidx, Wpr, br1p, w1t, w2t, b1p, flags);
  k1_router<<<512, 256, 0, stream>>>(hidden, feat, ln_g, ln_b, Wr1, Wr2, br2, seqlen,
                                     sidx, Wpr, br1p, flags, outG, outP, hws, cnt,
                                     listTok, smapG);
  k2_experts<<<2056, 256, 0, stream>>>(feat, hws, w1t, w2t, b1p, be2, eidx,
                                       cnt, listTok, flags, eoTok);
  k3_combine<<<1024, 256, 0, stream>>>(hidden, smapG, eoTok, alpha, outN);
}